// Round 10
// baseline (429.005 us; speedup 1.0000x reference)
//
#include <hip/hip_runtime.h>
#include <hip/hip_fp16.h>

#define NN 2048

typedef _Float16 f16x8 __attribute__((ext_vector_type(8)));
typedef _Float16 f16x2 __attribute__((ext_vector_type(2)));
typedef float f32x4 __attribute__((ext_vector_type(4)));

// ---------------------------------------------------------------------------
// Prep (byte-identical to R8)
// ---------------------------------------------------------------------------
__global__ __launch_bounds__(256) void prep_kernel(
    const float* __restrict__ A, const float* __restrict__ Wp,
    const float* __restrict__ bp, const float* __restrict__ W1,
    const float* __restrict__ b1,
    _Float16* __restrict__ pa, _Float16* __restrict__ pb)
{
    __shared__ float projLDS[8][32];
    const int t = threadIdx.x;
    const int rl = t >> 5;
    const int k  = t & 31;
    const int row = blockIdx.x * 8 + rl;

    const float4* xa = (const float4*)(A + row * 64);
    const float4* wp = (const float4*)(Wp + k * 64);
    float acc = bp[k];
#pragma unroll
    for (int m = 0; m < 16; ++m) {
        float4 xv = xa[m], wv = wp[m];
        acc += xv.x * wv.x + xv.y * wv.y + xv.z * wv.z + xv.w * wv.w;
    }
    projLDS[rl][k] = acc;
    __syncthreads();

    const float4* w1a = (const float4*)(W1 + k * 64);
    const float4* w1b = (const float4*)(W1 + k * 64 + 32);
    const float4* pr  = (const float4*)(projLDS[rl]);
    float sa = b1[k], sb = 0.f;
#pragma unroll
    for (int m = 0; m < 8; ++m) {
        float4 p = pr[m], wa = w1a[m], wb = w1b[m];
        sa += p.x * wa.x + p.y * wa.y + p.z * wa.z + p.w * wa.w;
        sb += p.x * wb.x + p.y * wb.y + p.z * wb.z + p.w * wb.w;
    }
    pa[row * 32 + k] = (_Float16)sa;
    pb[row * 32 + k] = (_Float16)sb;
}

// ---------------------------------------------------------------------------
// Main (byte-identical to R8 — control; layer3 on MFMA)
// ---------------------------------------------------------------------------
__global__ __launch_bounds__(256, 8) void sim_kernel(
    const _Float16* __restrict__ pa, const _Float16* __restrict__ pb,
    const float* __restrict__ W2, const float* __restrict__ b2,
    const float* __restrict__ W3, const float* __restrict__ b3,
    float* __restrict__ out)
{
    __shared__ _Float16 paLDS[32 * 32];
    const int t    = threadIdx.x;
    const int lane = t & 63;
    const int wid  = t >> 6;
    const int i0 = (blockIdx.x >> 5) * 32;
    const int jb = (((blockIdx.x & 31) << 2) + wid) * 16;
    const int n  = lane & 15;
    const int q  = lane >> 4;

    ((uint2*)paLDS)[t] = ((const uint2*)(pa + (size_t)i0 * 32))[t];

    const f16x8 pbf = *(const f16x8*)(pb + (size_t)(jb + n) * 32 + q * 8);

    f16x8 w2f;
    {
        const float* w2r = W2 + n * 32 + q * 8;
#pragma unroll
        for (int e = 0; e < 8; ++e) w2f[e] = (_Float16)w2r[e];
    }

    f32x4 cinit;
#pragma unroll
    for (int r = 0; r < 4; ++r) cinit[r] = b2[q * 4 + r];

    f16x8 w3a;
#pragma unroll
    for (int e = 0; e < 8; ++e)
        w3a[e] = ((e & 1) == (n & 1)) ? (_Float16)W3[q * 4 + (e >> 1)]
                                      : (_Float16)0.f;

    const float b3v = b3[0];
    f32x4 cinit2;
#pragma unroll
    for (int r = 0; r < 4; ++r) cinit2[r] = b3v;

    const f16x8 zero = {};

    __syncthreads();

    float* outp = out + (size_t)(i0 + q) * NN + jb + n;

    union B2U { f16x8 v; f16x2 p[4]; };

#pragma unroll 2
    for (int tt = 0; tt < 8; ++tt) {
        const _Float16* base = &paLDS[(4 * tt) * 32 + q * 8];
        f16x8 a0 = *(const f16x8*)(base);
        f16x8 a1 = *(const f16x8*)(base + 32);
        f16x8 a2 = *(const f16x8*)(base + 64);
        f16x8 a3 = *(const f16x8*)(base + 96);
        f16x8 h0 = __builtin_elementwise_max(a0 + pbf, zero);
        f16x8 h1 = __builtin_elementwise_max(a1 + pbf, zero);
        f16x8 h2 = __builtin_elementwise_max(a2 + pbf, zero);
        f16x8 h3 = __builtin_elementwise_max(a3 + pbf, zero);

        f32x4 d0 = __builtin_amdgcn_mfma_f32_16x16x32_f16(w2f, h0, cinit, 0, 0, 0);
        f32x4 d1 = __builtin_amdgcn_mfma_f32_16x16x32_f16(w2f, h1, cinit, 0, 0, 0);
        f32x4 d2 = __builtin_amdgcn_mfma_f32_16x16x32_f16(w2f, h2, cinit, 0, 0, 0);
        f32x4 d3 = __builtin_amdgcn_mfma_f32_16x16x32_f16(w2f, h3, cinit, 0, 0, 0);

        B2U pk01, pk23;
#pragma unroll
        for (int r = 0; r < 4; ++r) {
            pk01.p[r] = __builtin_bit_cast(f16x2,
                __builtin_amdgcn_cvt_pkrtz(fmaxf(d0[r], 0.f), fmaxf(d1[r], 0.f)));
            pk23.p[r] = __builtin_bit_cast(f16x2,
                __builtin_amdgcn_cvt_pkrtz(fmaxf(d2[r], 0.f), fmaxf(d3[r], 0.f)));
        }
        f32x4 l01 = __builtin_amdgcn_mfma_f32_16x16x32_f16(w3a, pk01.v, cinit2, 0, 0, 0);
        f32x4 l23 = __builtin_amdgcn_mfma_f32_16x16x32_f16(w3a, pk23.v, cinit2, 0, 0, 0);

        const float z = q == 0 ? l01[0] : q == 1 ? l01[1]
                      : q == 2 ? l23[0] : l23[1];
        float sim = __builtin_amdgcn_rcpf(1.f + __expf(-z));
        if (i0 + 4 * tt + q == jb + n) sim = 1.f;
        outp[(size_t)(4 * tt) * NN] = sim;
    }
}

// ---------------------------------------------------------------------------
// PROBES (diagnostic, this round only): nested prefixes of the R8 tt-loop.
//   V=0: ds_read + h1 only            (REPS=32)
//   V=1: + 4x layer-2 MFMA            (REPS=24)
//   V=2: full (pack + layer-3 + exp)  (REPS=8)
// asm "+v" on pq per rep defeats LICM; empty asm keepalives prevent DCE of
// the ablated tail (rule #17). per-rep time = row_dur / REPS.
// ---------------------------------------------------------------------------
template<int V, int REPS>
__global__ __launch_bounds__(256, 8) void probe_kernel(
    const _Float16* __restrict__ pa, const _Float16* __restrict__ pb,
    const float* __restrict__ W2, const float* __restrict__ b2,
    const float* __restrict__ W3, const float* __restrict__ b3,
    float* __restrict__ pout)
{
    __shared__ _Float16 paLDS[32 * 32];
    const int t    = threadIdx.x;
    const int lane = t & 63;
    const int wid  = t >> 6;
    const int gwid = blockIdx.x * 4 + wid;
    const int i0 = (blockIdx.x >> 5) * 32;
    const int jb = (((blockIdx.x & 31) << 2) + wid) * 16;
    const int n  = lane & 15;
    const int q  = lane >> 4;

    ((uint2*)paLDS)[t] = ((const uint2*)(pa + (size_t)i0 * 32))[t];

    f16x8 pbf = *(const f16x8*)(pb + (size_t)(jb + n) * 32 + q * 8);

    f16x8 w2f;
    {
        const float* w2r = W2 + n * 32 + q * 8;
#pragma unroll
        for (int e = 0; e < 8; ++e) w2f[e] = (_Float16)w2r[e];
    }

    f32x4 cinit;
#pragma unroll
    for (int r = 0; r < 4; ++r) cinit[r] = b2[q * 4 + r];

    f16x8 w3a;
#pragma unroll
    for (int e = 0; e < 8; ++e)
        w3a[e] = ((e & 1) == (n & 1)) ? (_Float16)W3[q * 4 + (e >> 1)]
                                      : (_Float16)0.f;

    const float b3v = b3[0];
    f32x4 cinit2;
#pragma unroll
    for (int r = 0; r < 4; ++r) cinit2[r] = b3v;

    const f16x8 zero = {};

    __syncthreads();

    union B2U { f16x8 v; f16x2 p[4]; };
    float acc = 0.f;

    for (int rep = 0; rep < REPS; ++rep) {
        f16x8 pq = pbf;
        asm volatile("" : "+v"(pq));          // defeat LICM across reps
#pragma unroll 2
        for (int tt = 0; tt < 8; ++tt) {
            const _Float16* base = &paLDS[(4 * tt) * 32 + q * 8];
            f16x8 a0 = *(const f16x8*)(base);
            f16x8 a1 = *(const f16x8*)(base + 32);
            f16x8 a2 = *(const f16x8*)(base + 64);
            f16x8 a3 = *(const f16x8*)(base + 96);
            f16x8 h0 = __builtin_elementwise_max(a0 + pq, zero);
            f16x8 h1 = __builtin_elementwise_max(a1 + pq, zero);
            f16x8 h2 = __builtin_elementwise_max(a2 + pq, zero);
            f16x8 h3 = __builtin_elementwise_max(a3 + pq, zero);

            if constexpr (V == 0) {
                asm volatile("" :: "v"(h0), "v"(h1), "v"(h2), "v"(h3));
                continue;
            }

            f32x4 d0 = __builtin_amdgcn_mfma_f32_16x16x32_f16(w2f, h0, cinit, 0, 0, 0);
            f32x4 d1 = __builtin_amdgcn_mfma_f32_16x16x32_f16(w2f, h1, cinit, 0, 0, 0);
            f32x4 d2 = __builtin_amdgcn_mfma_f32_16x16x32_f16(w2f, h2, cinit, 0, 0, 0);
            f32x4 d3 = __builtin_amdgcn_mfma_f32_16x16x32_f16(w2f, h3, cinit, 0, 0, 0);

            if constexpr (V == 1) {
                asm volatile("" :: "v"(d0), "v"(d1), "v"(d2), "v"(d3));
                continue;
            }

            B2U pk01, pk23;
#pragma unroll
            for (int r = 0; r < 4; ++r) {
                pk01.p[r] = __builtin_bit_cast(f16x2,
                    __builtin_amdgcn_cvt_pkrtz(fmaxf(d0[r], 0.f), fmaxf(d1[r], 0.f)));
                pk23.p[r] = __builtin_bit_cast(f16x2,
                    __builtin_amdgcn_cvt_pkrtz(fmaxf(d2[r], 0.f), fmaxf(d3[r], 0.f)));
            }
            f32x4 l01 = __builtin_amdgcn_mfma_f32_16x16x32_f16(w3a, pk01.v, cinit2, 0, 0, 0);
            f32x4 l23 = __builtin_amdgcn_mfma_f32_16x16x32_f16(w3a, pk23.v, cinit2, 0, 0, 0);

            const float z = q == 0 ? l01[0] : q == 1 ? l01[1]
                          : q == 2 ? l23[0] : l23[1];
            acc += __builtin_amdgcn_rcpf(1.f + __expf(-z));
        }
    }
    pout[(size_t)gwid * 64 + lane] = acc;
}

extern "C" void kernel_launch(void* const* d_in, const int* in_sizes, int n_in,
                              void* d_out, int out_size, void* d_ws, size_t ws_size,
                              hipStream_t stream)
{
    const float* A  = (const float*)d_in[0];
    const float* Wp = (const float*)d_in[1];
    const float* bp = (const float*)d_in[2];
    const float* W1 = (const float*)d_in[3];
    const float* b1 = (const float*)d_in[4];
    const float* W2 = (const float*)d_in[5];
    const float* b2 = (const float*)d_in[6];
    const float* W3 = (const float*)d_in[7];
    const float* b3 = (const float*)d_in[8];
    float* out = (float*)d_out;

    _Float16* pa = (_Float16*)d_ws;        // 2048*32 f16 = 128 KB
    _Float16* pb = pa + NN * 32;           // next 128 KB
    float* pout = (float*)((char*)d_ws + (32u << 20));  // probe scratch @ +32MB

    prep_kernel<<<NN / 8, 256, 0, stream>>>(A, Wp, bp, W1, b1, pa, pb);
    sim_kernel<<<2048, 256, 0, stream>>>(pa, pb, W2, b2, W3, b3, out);
    probe_kernel<0, 32><<<2048, 256, 0, stream>>>(pa, pb, W2, b2, W3, b3, pout);
    probe_kernel<1, 24><<<2048, 256, 0, stream>>>(pa, pb, W2, b2, W3, b3, pout);
    probe_kernel<2,  8><<<2048, 256, 0, stream>>>(pa, pb, W2, b2, W3, b3, pout);
}

// Round 11
// 95.755 us; speedup vs baseline: 4.4802x; 4.4802x over previous
//
#include <hip/hip_runtime.h>
#include <hip/hip_fp16.h>

#define NN 2048

typedef _Float16 f16x8 __attribute__((ext_vector_type(8)));
typedef _Float16 f16x2 __attribute__((ext_vector_type(2)));
typedef float f32x4 __attribute__((ext_vector_type(4)));

// ---------------------------------------------------------------------------
// Prep: proj = A@Wp.T + bp  (2048x32), then
//       pa'  = proj@Wa.T + b1  (f16, b1 folded),  pb = proj@Wb.T (f16)
// Wa = W1[:, :32], Wb = W1[:, 32:].  Block = 256 threads = 8 rows x 32 k.
// ---------------------------------------------------------------------------
__global__ __launch_bounds__(256) void prep_kernel(
    const float* __restrict__ A, const float* __restrict__ Wp,
    const float* __restrict__ bp, const float* __restrict__ W1,
    const float* __restrict__ b1,
    _Float16* __restrict__ pa, _Float16* __restrict__ pb)
{
    __shared__ float projLDS[8][32];
    const int t = threadIdx.x;
    const int rl = t >> 5;
    const int k  = t & 31;
    const int row = blockIdx.x * 8 + rl;

    const float4* xa = (const float4*)(A + row * 64);
    const float4* wp = (const float4*)(Wp + k * 64);
    float acc = bp[k];
#pragma unroll
    for (int m = 0; m < 16; ++m) {
        float4 xv = xa[m], wv = wp[m];
        acc += xv.x * wv.x + xv.y * wv.y + xv.z * wv.z + xv.w * wv.w;
    }
    projLDS[rl][k] = acc;
    __syncthreads();

    const float4* w1a = (const float4*)(W1 + k * 64);
    const float4* w1b = (const float4*)(W1 + k * 64 + 32);
    const float4* pr  = (const float4*)(projLDS[rl]);
    float sa = b1[k], sb = 0.f;
#pragma unroll
    for (int m = 0; m < 8; ++m) {
        float4 p = pr[m], wa = w1a[m], wb = w1b[m];
        sa += p.x * wa.x + p.y * wa.y + p.z * wa.z + p.w * wa.w;
        sb += p.x * wb.x + p.y * wb.y + p.z * wb.z + p.w * wb.w;
    }
    pa[row * 32 + k] = (_Float16)sa;
    pb[row * 32 + k] = (_Float16)sb;
}

// ---------------------------------------------------------------------------
// Main (R8 structure — best verified): one wave owns a 32i x 16j tile;
// 4 waves/block share the 32-row pa tile (2 KB LDS).
// Layer 2: D[h=16][pair=16] = W2 . relu(pa+pb), k=32, 1 MFMA per i.
// Layer 3 on the MFMA pipe: pack relu(d) pairs via v_cvt_pkrtz into a
// parity-interleaved B-operand; constant parity-gated A2 carries W3; D2 row
// parity = i-parity, b3 via C-init. Fragment maps m89/m74-verified; A/B
// share the element->k pairing so the common k-permutation cancels.
// R10 probe decomposition: h1 phase 4.5us, +MFMA 0.8us, +epilogue ~2us
// => sim ~7.5us total; dur_us is dominated by ~85us of harness poison
// fills (80-84% HBM peak). Kernel deltas are inside fill noise.
// ---------------------------------------------------------------------------
__global__ __launch_bounds__(256, 8) void sim_kernel(
    const _Float16* __restrict__ pa, const _Float16* __restrict__ pb,
    const float* __restrict__ W2, const float* __restrict__ b2,
    const float* __restrict__ W3, const float* __restrict__ b3,
    float* __restrict__ out)
{
    __shared__ _Float16 paLDS[32 * 32];
    const int t    = threadIdx.x;
    const int lane = t & 63;
    const int wid  = t >> 6;
    const int i0 = (blockIdx.x >> 5) * 32;
    const int jb = (((blockIdx.x & 31) << 2) + wid) * 16;
    const int n  = lane & 15;
    const int q  = lane >> 4;

    ((uint2*)paLDS)[t] = ((const uint2*)(pa + (size_t)i0 * 32))[t];

    const f16x8 pbf = *(const f16x8*)(pb + (size_t)(jb + n) * 32 + q * 8);

    f16x8 w2f;
    {
        const float* w2r = W2 + n * 32 + q * 8;
#pragma unroll
        for (int e = 0; e < 8; ++e) w2f[e] = (_Float16)w2r[e];
    }

    f32x4 cinit;
#pragma unroll
    for (int r = 0; r < 4; ++r) cinit[r] = b2[q * 4 + r];

    f16x8 w3a;
#pragma unroll
    for (int e = 0; e < 8; ++e)
        w3a[e] = ((e & 1) == (n & 1)) ? (_Float16)W3[q * 4 + (e >> 1)]
                                      : (_Float16)0.f;

    const float b3v = b3[0];
    f32x4 cinit2;
#pragma unroll
    for (int r = 0; r < 4; ++r) cinit2[r] = b3v;

    const f16x8 zero = {};

    __syncthreads();

    float* outp = out + (size_t)(i0 + q) * NN + jb + n;

    union B2U { f16x8 v; f16x2 p[4]; };

#pragma unroll 2
    for (int tt = 0; tt < 8; ++tt) {
        const _Float16* base = &paLDS[(4 * tt) * 32 + q * 8];
        f16x8 a0 = *(const f16x8*)(base);
        f16x8 a1 = *(const f16x8*)(base + 32);
        f16x8 a2 = *(const f16x8*)(base + 64);
        f16x8 a3 = *(const f16x8*)(base + 96);
        f16x8 h0 = __builtin_elementwise_max(a0 + pbf, zero);
        f16x8 h1 = __builtin_elementwise_max(a1 + pbf, zero);
        f16x8 h2 = __builtin_elementwise_max(a2 + pbf, zero);
        f16x8 h3 = __builtin_elementwise_max(a3 + pbf, zero);

        f32x4 d0 = __builtin_amdgcn_mfma_f32_16x16x32_f16(w2f, h0, cinit, 0, 0, 0);
        f32x4 d1 = __builtin_amdgcn_mfma_f32_16x16x32_f16(w2f, h1, cinit, 0, 0, 0);
        f32x4 d2 = __builtin_amdgcn_mfma_f32_16x16x32_f16(w2f, h2, cinit, 0, 0, 0);
        f32x4 d3 = __builtin_amdgcn_mfma_f32_16x16x32_f16(w2f, h3, cinit, 0, 0, 0);

        B2U pk01, pk23;
#pragma unroll
        for (int r = 0; r < 4; ++r) {
            pk01.p[r] = __builtin_bit_cast(f16x2,
                __builtin_amdgcn_cvt_pkrtz(fmaxf(d0[r], 0.f), fmaxf(d1[r], 0.f)));
            pk23.p[r] = __builtin_bit_cast(f16x2,
                __builtin_amdgcn_cvt_pkrtz(fmaxf(d2[r], 0.f), fmaxf(d3[r], 0.f)));
        }
        f32x4 l01 = __builtin_amdgcn_mfma_f32_16x16x32_f16(w3a, pk01.v, cinit2, 0, 0, 0);
        f32x4 l23 = __builtin_amdgcn_mfma_f32_16x16x32_f16(w3a, pk23.v, cinit2, 0, 0, 0);

        const float z = q == 0 ? l01[0] : q == 1 ? l01[1]
                      : q == 2 ? l23[0] : l23[1];
        float sim = __builtin_amdgcn_rcpf(1.f + __expf(-z));
        if (i0 + 4 * tt + q == jb + n) sim = 1.f;
        outp[(size_t)(4 * tt) * NN] = sim;
    }
}

extern "C" void kernel_launch(void* const* d_in, const int* in_sizes, int n_in,
                              void* d_out, int out_size, void* d_ws, size_t ws_size,
                              hipStream_t stream)
{
    const float* A  = (const float*)d_in[0];
    const float* Wp = (const float*)d_in[1];
    const float* bp = (const float*)d_in[2];
    const float* W1 = (const float*)d_in[3];
    const float* b1 = (const float*)d_in[4];
    const float* W2 = (const float*)d_in[5];
    const float* b2 = (const float*)d_in[6];
    const float* W3 = (const float*)d_in[7];
    const float* b3 = (const float*)d_in[8];
    float* out = (float*)d_out;

    _Float16* pa = (_Float16*)d_ws;        // 2048*32 f16 = 128 KB
    _Float16* pb = pa + NN * 32;           // next 128 KB

    prep_kernel<<<NN / 8, 256, 0, stream>>>(A, Wp, bp, W1, b1, pa, pb);
    sim_kernel<<<2048, 256, 0, stream>>>(pa, pb, W2, b2, W3, b3, out);
}